// Round 1
// baseline (64590.295 us; speedup 1.0000x reference)
//
#include <hip/hip_runtime.h>
#include <cstdint>
#include <cstddef>

// FBRNN: T=16384 steps, F=2048 input, H=16 hidden, A=64 attn, L=6 layers, G=3H=48.
// Phase 1 (parallel): gi0[t][g] = batch[t] . W_ih0[g] + b_ih0[g]   (T x 48)
// Phase 2 (sequential scan, 1 block): GRU chain + attention combine + fc per step.

#define TT 16384
#define FF 2048
#define HH 16
#define AA 64
#define LL 6
#define GG 48

// Static device scratch for gi0 (fully rewritten every call; no reliance on d_ws size).
__device__ float g_gi0[TT * GG];

__device__ __forceinline__ float sigmoid_f(float x) { return 1.f / (1.f + __expf(-x)); }
// tanh robust at +/-inf arguments of exp
__device__ __forceinline__ float tanh_f(float x) { return 1.f - 2.f / (__expf(2.f * x) + 1.f); }
__device__ __forceinline__ float rdlane(float v, int l) {
  union { float f; int i; } a, b;
  a.f = v;
  b.i = __builtin_amdgcn_readlane(a.i, l);
  return b.f;
}

// ---------------- Phase 1: gi0 GEMM ----------------
// Block: 256 threads handles 64 timesteps x 48 gates. K staged in 128-chunks.
__global__ __launch_bounds__(256) void gi0_gemm(const float* __restrict__ X,
                                                const float* __restrict__ W,
                                                const float* __restrict__ bias) {
  __shared__ float xs[64][132];  // pad 4 -> 16B-aligned rows, spread banks
  __shared__ float ws[48][132];
  const int tid = threadIdx.x;
  const int t0 = blockIdx.x * 64;
  const int tg = tid & 15;   // gate group: g = tg*3 + v
  const int tt = tid >> 4;   // 0..15 : t rows tt, tt+16, tt+32, tt+48
  float acc[4][3];
#pragma unroll
  for (int u = 0; u < 4; ++u)
#pragma unroll
    for (int v = 0; v < 3; ++v) acc[u][v] = 0.f;

  for (int k0 = 0; k0 < FF; k0 += 128) {
#pragma unroll
    for (int i = 0; i < 32; ++i) {  // 64*128 elements
      int e = tid + 256 * i;
      int r = e >> 7, c = e & 127;
      xs[r][c] = X[(size_t)(t0 + r) * FF + k0 + c];
    }
#pragma unroll
    for (int i = 0; i < 24; ++i) {  // 48*128 elements
      int e = tid + 256 * i;
      int r = e >> 7, c = e & 127;
      ws[r][c] = W[(size_t)r * FF + k0 + c];
    }
    __syncthreads();
#pragma unroll 8
    for (int c = 0; c < 128; ++c) {
      float x0 = xs[tt][c], x1 = xs[tt + 16][c], x2 = xs[tt + 32][c], x3 = xs[tt + 48][c];
      float w0 = ws[tg * 3 + 0][c], w1 = ws[tg * 3 + 1][c], w2 = ws[tg * 3 + 2][c];
      acc[0][0] += x0 * w0; acc[0][1] += x0 * w1; acc[0][2] += x0 * w2;
      acc[1][0] += x1 * w0; acc[1][1] += x1 * w1; acc[1][2] += x1 * w2;
      acc[2][0] += x2 * w0; acc[2][1] += x2 * w1; acc[2][2] += x2 * w2;
      acc[3][0] += x3 * w0; acc[3][1] += x3 * w1; acc[3][2] += x3 * w2;
    }
    __syncthreads();
  }
#pragma unroll
  for (int u = 0; u < 4; ++u)
#pragma unroll
    for (int v = 0; v < 3; ++v)
      g_gi0[(size_t)(t0 + tt + 16 * u) * GG + tg * 3 + v] = acc[u][v] + bias[tg * 3 + v];
}

// ---------------- Phase 2: sequential scan ----------------
// 1 block x 256 threads (4 waves). Weights in registers, activations in LDS.
// Per step: [A] all 288 gh dots (parallel) | barrier | [B] 6-layer GRU chain in
// wave0 (shfl/readlane, no LDS in dep chain) | barrier | [C] combine i=0..4 split
// across waves + h5 copy + fc | barrier.
__global__ __launch_bounds__(256, 1) void fbrnn_scan(
    const float* __restrict__ h0,
    const float* __restrict__ Whh0, const float* __restrict__ bhh0,
    const float* __restrict__ Wih, const float* __restrict__ Whh,
    const float* __restrict__ bih, const float* __restrict__ bhh,
    const float* __restrict__ Wa, const float* __restrict__ ba,
    const float* __restrict__ va,
    const float* __restrict__ fc1w, const float* __restrict__ fc1b,
    const float* __restrict__ fc2w, const float* __restrict__ fc2b,
    float* __restrict__ out) {
  __shared__ __align__(16) float hS[LL][HH];   // carried hidden states
  __shared__ __align__(16) float nsS[LL][HH];  // this step's newS
  __shared__ __align__(16) float ghS[LL][GG];  // gh pre-activations

  const int tid = threadIdx.x;
  const int wv = tid >> 6;
  const int lane = tid & 63;
  const int g48 = lane < 48 ? lane : 47;  // clamped gate index (wave0 chain)
  const int k16 = lane & 15;

  // ---- register weight load (indices clamped so all regs are defined) ----
  // gh task 1: (l,g) = (tid/48, tid%48); task 2 (tid<32): l=5, g=16+tid
  const int gl = tid / 48;
  const int gg = tid % 48;
  float WhhR[16], WhhR2[16], bhhR, bhhR2;
  {
    const float* src = (gl == 0) ? (Whh0 + gg * 16) : (Whh + ((gl - 1) * 48 + gg) * 16);
#pragma unroll
    for (int k = 0; k < 16; ++k) WhhR[k] = src[k];
    bhhR = (gl == 0) ? bhh0[gg] : bhh[(gl - 1) * 48 + gg];
    const int g2 = 16 + (tid & 31);
    const float* src2 = Whh + (4 * 48 + g2) * 16;
#pragma unroll
    for (int k = 0; k < 16; ++k) WhhR2[k] = src2[k];
    bhhR2 = bhh[4 * 48 + g2];
  }
  // Wih rows for layers 1..5 (used by wave0 lane g)
  float WihR[5][16], bihR[5];
#pragma unroll
  for (int l = 0; l < 5; ++l) {
    const float* src = Wih + (l * 48 + g48) * 16;
#pragma unroll
    for (int k = 0; k < 16; ++k) WihR[l][k] = src[k];
    bihR[l] = bih[l * 48 + g48];
  }
  // combine: wave -> attention rows. w0:{3,4} w1:{0} w2:{1} w3:{2}
  const int ciA = (wv == 0) ? 3 : (wv - 1);
  float WaA[16], WaB[16], baA, baB, vaA, vaB;
  {
    const int iA = ciA, iB = 4;  // iB only used by wave0
#pragma unroll
    for (int k = 0; k < 16; ++k) {
      WaA[k] = Wa[(iA * 16 + k) * 64 + lane];
      WaB[k] = Wa[(iB * 16 + k) * 64 + lane];
    }
    baA = ba[iA * 64 + lane]; baB = ba[iB * 64 + lane];
    vaA = va[iA * 64 + lane]; vaB = va[iB * 64 + lane];
  }
  // fc (wave3 lanes 0..31 meaningful)
  float fc1R[16], fc1bR, fc2wR, fc2bR;
  {
    const int m = lane & 31;
#pragma unroll
    for (int k = 0; k < 16; ++k) fc1R[k] = fc1w[m * 16 + k];
    fc1bR = fc1b[m]; fc2wR = fc2w[m]; fc2bR = fc2b[0];
  }

  if (tid < 96) ((float*)hS)[tid] = h0[tid];
  __syncthreads();

  auto combine_one = [&](int i, const float (&WaR)[16], float baR, float vaR) {
    float Erow[6];
#pragma unroll
    for (int j = 0; j < 6; ++j) {
      float e = -1e30f;
      if (j >= i) {  // wave-uniform branch
        const float4* np = reinterpret_cast<const float4*>(nsS[j]);
        float4 a0 = np[0], a1 = np[1], a2 = np[2], a3 = np[3];
        float u = baR;
        u += WaR[0] * a0.x + WaR[1] * a0.y + WaR[2] * a0.z + WaR[3] * a0.w;
        u += WaR[4] * a1.x + WaR[5] * a1.y + WaR[6] * a1.z + WaR[7] * a1.w;
        u += WaR[8] * a2.x + WaR[9] * a2.y + WaR[10] * a2.z + WaR[11] * a2.w;
        u += WaR[12] * a3.x + WaR[13] * a3.y + WaR[14] * a3.z + WaR[15] * a3.w;
        float p = vaR * tanh_f(u);  // va[a] * tanh(.), a = lane (A=64)
        p += __shfl_xor(p, 32);
        p += __shfl_xor(p, 16);
        p += __shfl_xor(p, 8);
        p += __shfl_xor(p, 4);
        p += __shfl_xor(p, 2);
        p += __shfl_xor(p, 1);
        e = p;
      }
      Erow[j] = e;
    }
    float mx = Erow[0];
#pragma unroll
    for (int j = 1; j < 6; ++j) mx = fmaxf(mx, Erow[j]);
    float wj[6], s = 0.f;
#pragma unroll
    for (int j = 0; j < 6; ++j) {
      float w = (j >= i) ? __expf(Erow[j] - mx) : 0.f;
      wj[j] = w; s += w;
    }
    const float inv = 1.f / s;
    float acc = 0.f;
#pragma unroll
    for (int j = 0; j < 6; ++j) acc += wj[j] * nsS[j][k16];
    if (lane < 16) hS[i][k16] = acc * inv;
  };

#pragma unroll 1
  for (int t = 0; t < TT; ++t) {
    // wave0 prefetch of this step's gi0 row (overlaps phase A)
    float gi_t = 0.f;
    if (wv == 0) gi_t = g_gi0[(size_t)t * GG + g48];

    // ---- Phase A: gh[l][g] = bhh + Whh[l][g,:] . h[l] ----
    {
      const float4* hp = reinterpret_cast<const float4*>(hS[gl]);
      float4 a0 = hp[0], a1 = hp[1], a2 = hp[2], a3 = hp[3];
      float acc = bhhR;
      acc += WhhR[0] * a0.x + WhhR[1] * a0.y + WhhR[2] * a0.z + WhhR[3] * a0.w;
      acc += WhhR[4] * a1.x + WhhR[5] * a1.y + WhhR[6] * a1.z + WhhR[7] * a1.w;
      acc += WhhR[8] * a2.x + WhhR[9] * a2.y + WhhR[10] * a2.z + WhhR[11] * a2.w;
      acc += WhhR[12] * a3.x + WhhR[13] * a3.y + WhhR[14] * a3.z + WhhR[15] * a3.w;
      ghS[gl][gg] = acc;
      if (tid < 32) {
        const float4* hp2 = reinterpret_cast<const float4*>(hS[5]);
        float4 b0 = hp2[0], b1 = hp2[1], b2 = hp2[2], b3 = hp2[3];
        float acc2 = bhhR2;
        acc2 += WhhR2[0] * b0.x + WhhR2[1] * b0.y + WhhR2[2] * b0.z + WhhR2[3] * b0.w;
        acc2 += WhhR2[4] * b1.x + WhhR2[5] * b1.y + WhhR2[6] * b1.z + WhhR2[7] * b1.w;
        acc2 += WhhR2[8] * b2.x + WhhR2[9] * b2.y + WhhR2[10] * b2.z + WhhR2[11] * b2.w;
        acc2 += WhhR2[12] * b3.x + WhhR2[13] * b3.y + WhhR2[14] * b3.z + WhhR2[15] * b3.w;
        ghS[5][16 + tid] = acc2;
      }
    }
    __syncthreads();  // barrier 1: gh ready

    // ---- Phase B: GRU chain, wave0 only, no barriers inside ----
    if (wv == 0) {
      float ghv[6], hv[6];
#pragma unroll
      for (int l = 0; l < 6; ++l) { ghv[l] = ghS[l][g48]; hv[l] = hS[l][k16]; }
      float nsb[16];
      float gi_g = gi_t;
#pragma unroll
      for (int l = 0; l < 6; ++l) {
        if (l > 0) {
          float d = bihR[l - 1];
#pragma unroll
          for (int k = 0; k < 16; ++k) d += WihR[l - 1][k] * nsb[k];
          gi_g = d;
        }
        const float gh_g = ghv[l];
        const float s_g = gi_g + gh_g;              // lane k: i_r + h_r
        const float zs = __shfl_down(s_g, 16);      // i_z + h_z
        const float gin = __shfl_down(gi_g, 32);    // i_n
        const float ghn = __shfl_down(gh_g, 32);    // h_n
        const float r = sigmoid_f(s_g);
        const float z = sigmoid_f(zs);
        const float n = tanh_f(gin + r * ghn);
        const float nsv = (1.f - z) * n + z * hv[l];
        if (lane < 16) nsS[l][lane] = nsv;
        if (l < 5) {
#pragma unroll
          for (int k = 0; k < 16; ++k) nsb[k] = rdlane(nsv, k);  // broadcast newS[l]
        }
      }
    }
    __syncthreads();  // barrier 2: newS ready

    // ---- Phase C: combine + h5 copy + fc ----
    if (wv == 2) {
      if (lane >= 16 && lane < 32) hS[5][lane - 16] = nsS[5][lane - 16];  // i=5: softmax(1)=1
    }
    combine_one(ciA, WaA, baA, vaA);
    if (wv == 0) combine_one(4, WaB, baB, vaB);
    if (wv == 3) {
      const float4* np = reinterpret_cast<const float4*>(nsS[5]);
      float4 a0 = np[0], a1 = np[1], a2 = np[2], a3 = np[3];
      float y = fc1bR;
      y += fc1R[0] * a0.x + fc1R[1] * a0.y + fc1R[2] * a0.z + fc1R[3] * a0.w;
      y += fc1R[4] * a1.x + fc1R[5] * a1.y + fc1R[6] * a1.z + fc1R[7] * a1.w;
      y += fc1R[8] * a2.x + fc1R[9] * a2.y + fc1R[10] * a2.z + fc1R[11] * a2.w;
      y += fc1R[12] * a3.x + fc1R[13] * a3.y + fc1R[14] * a3.z + fc1R[15] * a3.w;
      float p = y * fc2wR;  // lanes 0..31 hold fc1 outputs * fc2 weight
      p += __shfl_xor(p, 16);
      p += __shfl_xor(p, 8);
      p += __shfl_xor(p, 4);
      p += __shfl_xor(p, 2);
      p += __shfl_xor(p, 1);
      if (lane == 0) out[t] = p + fc2bR;
    }
    __syncthreads();  // barrier 3: hS updated for next step
  }
}

extern "C" void kernel_launch(void* const* d_in, const int* in_sizes, int n_in,
                              void* d_out, int out_size, void* d_ws, size_t ws_size,
                              hipStream_t stream) {
  const float* batch = (const float*)d_in[0];
  const float* h0    = (const float*)d_in[1];
  const float* Wih0  = (const float*)d_in[2];
  const float* Whh0  = (const float*)d_in[3];
  const float* bih0  = (const float*)d_in[4];
  const float* bhh0  = (const float*)d_in[5];
  const float* Wih   = (const float*)d_in[6];
  const float* Whh   = (const float*)d_in[7];
  const float* bih   = (const float*)d_in[8];
  const float* bhh   = (const float*)d_in[9];
  const float* Wa    = (const float*)d_in[10];
  const float* ba    = (const float*)d_in[11];
  const float* va    = (const float*)d_in[12];
  const float* fc1w  = (const float*)d_in[13];
  const float* fc1b  = (const float*)d_in[14];
  const float* fc2w  = (const float*)d_in[15];
  const float* fc2b  = (const float*)d_in[16];
  float* out = (float*)d_out;
  (void)in_sizes; (void)n_in; (void)out_size; (void)d_ws; (void)ws_size;

  gi0_gemm<<<TT / 64, 256, 0, stream>>>(batch, Wih0, bih0);
  fbrnn_scan<<<1, 256, 0, stream>>>(h0, Whh0, bhh0, Wih, Whh, bih, bhh,
                                    Wa, ba, va, fc1w, fc1b, fc2w, fc2b, out);
}

// Round 2
// 37259.271 us; speedup vs baseline: 1.7335x; 1.7335x over previous
//
#include <hip/hip_runtime.h>
#include <cstdint>
#include <cstddef>

// FBRNN: T=16384, F=2048, H=16, A=64, L=6, G=3H=48.
// gi0 GEMM precomputed in permuted layout [t][k*4+gate] (gate: 0=r,1=z,2=n, 3=pad).
// Scan: 1 block x 256 threads. Per step only 2 barriers:
//   B: wave0 runs the 6-layer GRU chain (gate-interleaved lanes, DPP quad bcast,
//      readlane newS broadcast, zero ds in dep chain)
//   C: waves1-3 do attention combine (lane=a, DPP rowsum + readlane reduction,
//      in-register softmax) AND the next step's gh rows; wave0 does fc + gh[5].

#define TT 16384
#define FF 2048
#define HH 16
#define AA 64
#define LL 6
#define GG 48

__device__ float g_gi0p[(TT + 1) * 64];  // +1 row: prefetch overrun pad

__device__ __forceinline__ float sigmoid_f(float x) { return 1.f / (1.f + __expf(-x)); }
__device__ __forceinline__ float tanh_f(float x) { return 1.f - 2.f / (__expf(2.f * x) + 1.f); }

__device__ __forceinline__ float rdlane(float v, int l) {
  union { float f; int i; } a, b;
  a.f = v; b.i = __builtin_amdgcn_readlane(a.i, l); return b.f;
}
template <int CTRL>
__device__ __forceinline__ float dppf(float v) {
  union { float f; int i; } a, b;
  a.f = v; b.i = __builtin_amdgcn_mov_dpp(a.i, CTRL, 0xF, 0xF, true); return b.f;
}
template <int Q>  // broadcast quad lane Q to all 4 lanes of the quad
__device__ __forceinline__ float qbcast(float v) { return dppf<Q | (Q << 2) | (Q << 4) | (Q << 6)>(v); }

// sum within each 16-lane row: xor1, xor2, then mirror tricks (valid once groups uniform)
__device__ __forceinline__ float rowsum16(float v) {
  v += dppf<0xB1>(v);   // quad_perm [1,0,3,2]  == xor1
  v += dppf<0x4E>(v);   // quad_perm [2,3,0,1]  == xor2
  v += dppf<0x141>(v);  // row_half_mirror (xor7 == xor4 once quads uniform)
  v += dppf<0x140>(v);  // row_mirror      (xor15 == xor8 once octs uniform)
  return v;
}
__device__ __forceinline__ float wavesum64(float v) {
  v = rowsum16(v);
  float a = rdlane(v, 0), b = rdlane(v, 16), c = rdlane(v, 32), d = rdlane(v, 48);
  return (a + b) + (c + d);
}
// dot16 where p is a wave-uniform LDS address (broadcast read)
__device__ __forceinline__ float dot16_bcast(const float (&w)[16], const float* p) {
  const float4* fp = (const float4*)p;
  float4 a0 = fp[0], a1 = fp[1], a2 = fp[2], a3 = fp[3];
  float s0 = w[0] * a0.x, s1 = w[1] * a0.y, s2 = w[2] * a0.z, s3 = w[3] * a0.w;
  s0 = fmaf(w[4], a1.x, s0);  s1 = fmaf(w[5], a1.y, s1);
  s2 = fmaf(w[6], a1.z, s2);  s3 = fmaf(w[7], a1.w, s3);
  s0 = fmaf(w[8], a2.x, s0);  s1 = fmaf(w[9], a2.y, s1);
  s2 = fmaf(w[10], a2.z, s2); s3 = fmaf(w[11], a2.w, s3);
  s0 = fmaf(w[12], a3.x, s0); s1 = fmaf(w[13], a3.y, s1);
  s2 = fmaf(w[14], a3.z, s2); s3 = fmaf(w[15], a3.w, s3);
  return (s0 + s1) + (s2 + s3);
}
// dot16 with h in (uniform) registers/sgprs
__device__ __forceinline__ float dot16r(const float (&w)[16], const float (&h)[16]) {
  float s0 = w[0] * h[0], s1 = w[1] * h[1], s2 = w[2] * h[2], s3 = w[3] * h[3];
#pragma unroll
  for (int k = 4; k < 16; k += 4) {
    s0 = fmaf(w[k], h[k], s0);     s1 = fmaf(w[k + 1], h[k + 1], s1);
    s2 = fmaf(w[k + 2], h[k + 2], s2); s3 = fmaf(w[k + 3], h[k + 3], s3);
  }
  return (s0 + s1) + (s2 + s3);
}

// ---------------- Phase 1: gi0 GEMM (permuted output) ----------------
__global__ __launch_bounds__(256) void gi0_gemm(const float* __restrict__ X,
                                                const float* __restrict__ W,
                                                const float* __restrict__ bias) {
  __shared__ float xs[64][132];
  __shared__ float ws[48][132];
  const int tid = threadIdx.x;
  const int t0 = blockIdx.x * 64;
  const int tg = tid & 15;   // hidden unit k; gates handled: tg, tg+16, tg+32
  const int tt = tid >> 4;   // t rows tt, tt+16, tt+32, tt+48
  float acc[4][3];
#pragma unroll
  for (int u = 0; u < 4; ++u)
#pragma unroll
    for (int v = 0; v < 3; ++v) acc[u][v] = 0.f;

  for (int k0 = 0; k0 < FF; k0 += 128) {
#pragma unroll
    for (int i = 0; i < 32; ++i) {
      int e = tid + 256 * i; int r = e >> 7, c = e & 127;
      xs[r][c] = X[(size_t)(t0 + r) * FF + k0 + c];
    }
#pragma unroll
    for (int i = 0; i < 24; ++i) {
      int e = tid + 256 * i; int r = e >> 7, c = e & 127;
      ws[r][c] = W[(size_t)r * FF + k0 + c];
    }
    __syncthreads();
#pragma unroll 8
    for (int c = 0; c < 128; ++c) {
      float x0 = xs[tt][c], x1 = xs[tt + 16][c], x2 = xs[tt + 32][c], x3 = xs[tt + 48][c];
      float w0 = ws[tg][c], w1 = ws[tg + 16][c], w2 = ws[tg + 32][c];
      acc[0][0] += x0 * w0; acc[0][1] += x0 * w1; acc[0][2] += x0 * w2;
      acc[1][0] += x1 * w0; acc[1][1] += x1 * w1; acc[1][2] += x1 * w2;
      acc[2][0] += x2 * w0; acc[2][1] += x2 * w1; acc[2][2] += x2 * w2;
      acc[3][0] += x3 * w0; acc[3][1] += x3 * w1; acc[3][2] += x3 * w2;
    }
    __syncthreads();
  }
#pragma unroll
  for (int u = 0; u < 4; ++u)
#pragma unroll
    for (int v = 0; v < 3; ++v)
      g_gi0p[(size_t)(t0 + tt + 16 * u) * 64 + tg * 4 + v] = acc[u][v] + bias[tg + 16 * v];
}

// ---------------- combine + fused gh for next step ----------------
// Lane = a (0..63). Energies for i=I0 (NJ0 rows j=I0..5) and optionally i=I1.
// Writer lanes 0-15 produce h[I0], 16-31 h[I1]. Then gh rows via readlane bcast.
template <int I0, int NJ0, int I1, int NJ1>
__device__ __forceinline__ void combine_block(
    int lane, const float* nsS, float* hS, float* ghS,
    const float (&WaR0)[16], float baR0, float vaR0,
    const float (&WaR1)[16], float baR1, float vaR1,
    const float (&WhhA)[16], float bhhA,
    const float (&WhhB)[16], float bhhB) {
  const int k16 = lane & 15;
  float nsv[6];
#pragma unroll
  for (int j = 0; j < 6; ++j) nsv[j] = nsS[j * 16 + k16];

  float e0[NJ0], e1[NJ1 > 0 ? NJ1 : 1];
#pragma unroll
  for (int j = I0; j < 6; ++j) {
    const float* nsj = nsS + j * 16;
    float u0 = baR0 + dot16_bcast(WaR0, nsj);
    float p0 = vaR0 * tanh_f(u0);
    e0[j - I0] = wavesum64(p0);
    if constexpr (NJ1 > 0) {
      if (j >= I1) {
        float u1 = baR1 + dot16_bcast(WaR1, nsj);
        float p1 = vaR1 * tanh_f(u1);
        e1[j - I1] = wavesum64(p1);
      }
    }
  }
  float hval;
  {
    float m = e0[0];
#pragma unroll
    for (int jj = 1; jj < NJ0; ++jj) m = fmaxf(m, e0[jj]);
    float s = 0.f, acc = 0.f;
#pragma unroll
    for (int jj = 0; jj < NJ0; ++jj) {
      float w = __expf(e0[jj] - m);
      s += w; acc = fmaf(w, nsv[I0 + jj], acc);
    }
    hval = acc / s;
  }
  if constexpr (NJ1 > 0) {
    float m = e1[0];
#pragma unroll
    for (int jj = 1; jj < NJ1; ++jj) m = fmaxf(m, e1[jj]);
    float s = 0.f, acc = 0.f;
#pragma unroll
    for (int jj = 0; jj < NJ1; ++jj) {
      float w = __expf(e1[jj] - m);
      s += w; acc = fmaf(w, nsv[I1 + jj], acc);
    }
    if (lane >= 16) hval = acc / s;   // lanes 16.. take I1's value
  }
  if (lane < (NJ1 > 0 ? 32 : 16)) hS[(lane < 16 ? I0 : I1) * 16 + k16] = hval;

  // fused gh rows for next step (h broadcast via readlane)
  float hA[16];
#pragma unroll
  for (int k = 0; k < 16; ++k) hA[k] = rdlane(hval, k);
  ghS[I0 * 64 + lane] = bhhA + dot16r(WhhA, hA);
  if constexpr (NJ1 > 0) {
    float hB[16];
#pragma unroll
    for (int k = 0; k < 16; ++k) hB[k] = rdlane(hval, 16 + k);
    ghS[I1 * 64 + lane] = bhhB + dot16r(WhhB, hB);
  }
}

// ---------------- Phase 2: sequential scan ----------------
__global__ __launch_bounds__(256, 1) void fbrnn_scan(
    const float* __restrict__ h0,
    const float* __restrict__ Whh0, const float* __restrict__ bhh0,
    const float* __restrict__ Wih, const float* __restrict__ Whh,
    const float* __restrict__ bih, const float* __restrict__ bhh,
    const float* __restrict__ Wa, const float* __restrict__ ba,
    const float* __restrict__ va,
    const float* __restrict__ fc1w, const float* __restrict__ fc1b,
    const float* __restrict__ fc2w, const float* __restrict__ fc2b,
    float* __restrict__ out) {
  __shared__ __align__(16) float hS[LL * HH];
  __shared__ __align__(16) float nsS[LL * HH];
  __shared__ __align__(16) float ghS[LL * 64];

  const int tid = threadIdx.x;
  const int wv = tid >> 6;
  const int lane = tid & 63;
  const int qg = lane & 3;         // gate within quad (0=r,1=z,2=n,3=dead)
  const int kk = lane >> 2;        // hidden unit
  const int G = (qg < 3 ? qg : 2) * 16 + kk;  // original gate row index

  // Register weight banks, role depends on wave:
  // wave0: WB[0..4]=Wih rows (layers 1..5), WB[5]=Whh layer5 row, WB[6]=fc1 row
  // waves1-3: WB[0]=Wa col i0, WB[1]=Wa col i1, WB[2]=Whh row i0, WB[3]=Whh row i1
  float WB[7][16];
  float bihR[5];
  float bhhA = 0.f, bhhB = 0.f, ba0v = 0.f, ba1v = 0.f, va0v = 0.f, va1v = 0.f;
  float fb1 = 0.f, fw2 = 0.f, fb2 = 0.f;

  if (wv == 0) {
#pragma unroll
    for (int l = 0; l < 5; ++l) {
#pragma unroll
      for (int k = 0; k < 16; ++k) WB[l][k] = Wih[((l * GG) + G) * 16 + k];
      bihR[l] = bih[l * GG + G];
    }
#pragma unroll
    for (int k = 0; k < 16; ++k) WB[5][k] = Whh[(4 * GG + G) * 16 + k];
    bhhA = bhh[4 * GG + G];
    const int m = lane & 31;
#pragma unroll
    for (int k = 0; k < 16; ++k) WB[6][k] = fc1w[m * 16 + k];
    fb1 = fc1b[m]; fw2 = fc2w[m]; fb2 = fc2b[0];
  } else {
    const int i0 = (wv == 1) ? 0 : (wv == 2) ? 1 : 2;
    const int i1 = (wv == 2) ? 4 : 3;
#pragma unroll
    for (int k = 0; k < 16; ++k) {
      WB[0][k] = Wa[(i0 * 16 + k) * 64 + lane];
      WB[1][k] = Wa[(i1 * 16 + k) * 64 + lane];
    }
    ba0v = ba[i0 * 64 + lane]; va0v = va[i0 * 64 + lane];
    ba1v = ba[i1 * 64 + lane]; va1v = va[i1 * 64 + lane];
    const float* wA = (i0 == 0) ? (Whh0 + G * 16) : (Whh + ((i0 - 1) * GG + G) * 16);
#pragma unroll
    for (int k = 0; k < 16; ++k) WB[2][k] = wA[k];
    bhhA = (i0 == 0) ? bhh0[G] : bhh[(i0 - 1) * GG + G];
    const float* wB = Whh + ((i1 - 1) * GG + G) * 16;
#pragma unroll
    for (int k = 0; k < 16; ++k) WB[3][k] = wB[k];
    bhhB = bhh[(i1 - 1) * GG + G];
  }

  if (tid < 96) hS[tid] = h0[tid];

  // initial gh from h0 (uniform s_loads), initial gi prefetch
  auto ghinit = [&](int i, const float (&W)[16], float b) {
    float h[16];
#pragma unroll
    for (int k = 0; k < 16; ++k) h[k] = h0[i * 16 + k];
    ghS[i * 64 + lane] = b + dot16r(W, h);
  };
  float gnext = 0.f;
  if (wv == 0) {
    gnext = g_gi0p[lane];
    ghinit(5, WB[5], bhhA);
  } else if (wv == 1) {
    ghinit(0, WB[2], bhhA);
  } else if (wv == 2) {
    ghinit(1, WB[2], bhhA); ghinit(4, WB[3], bhhB);
  } else {
    ghinit(2, WB[2], bhhA); ghinit(3, WB[3], bhhB);
  }
  __syncthreads();

#pragma unroll 1
  for (int t = 0; t < TT; ++t) {
    float ns5sg[16];
    // ---- Phase B: GRU chain (wave0), other waves head to barrier ----
    if (wv == 0) {
      float gpre = g_gi0p[(size_t)(t + 1) * 64 + lane];  // prefetch next step
      float ghv[6], hv[6];
#pragma unroll
      for (int l = 0; l < 6; ++l) { ghv[l] = ghS[l * 64 + lane]; hv[l] = hS[l * 16 + kk]; }
      float ns_sg[16];
      float gi = gnext;
#pragma unroll
      for (int l = 0; l < 6; ++l) {
        if (l > 0) gi = bihR[l - 1] + dot16r(WB[l - 1], ns_sg);
        const float s = gi + ghv[l];
        const float sg = sigmoid_f(s);            // valid at qg=0 (r), qg=1 (z)
        const float sr = qbcast<0>(sg);           // r broadcast to quad
        const float tq = tanh_f(fmaf(sr, ghv[l], gi));  // valid at qg=2 (n)
        const float nn = qbcast<2>(tq);
        const float sz = qbcast<1>(sg);
        const float ns = fmaf(sz, hv[l] - nn, nn);      // (1-z)n + z*h
        if (qg == 0) {
          nsS[l * 16 + kk] = ns;
          if (l == 5) hS[5 * 16 + kk] = ns;             // h[5] = newS[5]
        }
#pragma unroll
        for (int k = 0; k < 16; ++k) ns_sg[k] = rdlane(ns, 4 * k);
      }
#pragma unroll
      for (int k = 0; k < 16; ++k) ns5sg[k] = ns_sg[k];
      gnext = gpre;
    }
    __syncthreads();  // barrier A: nsS ready

    // ---- Phase C: combine + fused next-step gh; wave0: fc + gh[5] ----
    if (wv == 0) {
      float y = fb1 + dot16r(WB[6], ns5sg);   // fc1 (m = lane&31)
      float p = rowsum16(y * fw2);
      float sA = rdlane(p, 0), sB = rdlane(p, 16);
      if (lane == 0) out[t] = sA + sB + fb2;
      ghS[5 * 64 + lane] = bhhA + dot16r(WB[5], ns5sg);
    } else if (wv == 1) {
      combine_block<0, 6, 3, 0>(lane, nsS, hS, ghS, WB[0], ba0v, va0v,
                                WB[1], ba1v, va1v, WB[2], bhhA, WB[3], bhhB);
    } else if (wv == 2) {
      combine_block<1, 5, 4, 2>(lane, nsS, hS, ghS, WB[0], ba0v, va0v,
                                WB[1], ba1v, va1v, WB[2], bhhA, WB[3], bhhB);
    } else {
      combine_block<2, 4, 3, 3>(lane, nsS, hS, ghS, WB[0], ba0v, va0v,
                                WB[1], ba1v, va1v, WB[2], bhhA, WB[3], bhhB);
    }
    __syncthreads();  // barrier B: hS/ghS ready for next step
  }
}

extern "C" void kernel_launch(void* const* d_in, const int* in_sizes, int n_in,
                              void* d_out, int out_size, void* d_ws, size_t ws_size,
                              hipStream_t stream) {
  const float* batch = (const float*)d_in[0];
  const float* h0    = (const float*)d_in[1];
  const float* Wih0  = (const float*)d_in[2];
  const float* Whh0  = (const float*)d_in[3];
  const float* bih0  = (const float*)d_in[4];
  const float* bhh0  = (const float*)d_in[5];
  const float* Wih   = (const float*)d_in[6];
  const float* Whh   = (const float*)d_in[7];
  const float* bih   = (const float*)d_in[8];
  const float* bhh   = (const float*)d_in[9];
  const float* Wa    = (const float*)d_in[10];
  const float* ba    = (const float*)d_in[11];
  const float* va    = (const float*)d_in[12];
  const float* fc1w  = (const float*)d_in[13];
  const float* fc1b  = (const float*)d_in[14];
  const float* fc2w  = (const float*)d_in[15];
  const float* fc2b  = (const float*)d_in[16];
  float* out = (float*)d_out;
  (void)in_sizes; (void)n_in; (void)out_size; (void)d_ws; (void)ws_size;

  gi0_gemm<<<TT / 64, 256, 0, stream>>>(batch, Wih0, bih0);
  fbrnn_scan<<<1, 256, 0, stream>>>(h0, Whh0, bhh0, Wih, Whh, bih, bhh,
                                    Wa, ba, va, fc1w, fc1b, fc2w, fc2b, out);
}